// Round 15
// baseline (49.112 us; speedup 1.0000x reference)
//
#include <hip/hip_runtime.h>
#include <hip/hip_bf16.h>

// ConvexReLUCNN: B=512, C=3, H=W=64, KERNEL=3
//   K=27, L=62*62=3844, M=512, O=10
#define ODIM   10
#define HOg    62
#define LDIM   3844
#define CHW    12288
#define BATCH  512
#define KO     270
#define MDIM   512        // reduction dim (neurons)
#define LROW   72         // padded LDS row stride in bf16 (144 B)

typedef __attribute__((ext_vector_type(8))) short bfrag;   // 8 bf16 (4 VGPR)
typedef __attribute__((ext_vector_type(4))) float f32x4;

// ---------------------------------------------------------------------------
// K0 prep, 1572 blocks:
//   [0,496):     Gt[n][m] (bf16) = G[m][n], 64x64 LDS-tiled transpose (n<3968)
//   [496,1072):  Pdt[ko][m] (bf16) = v[m][ko]-w[m][ko] (ko>=270 -> 0), 288 rows
//   [1072,1552): S = 0   (tmfma scatter-accumulates into S)
//   [1552,1572): out = 0 (out_gemm accumulates with atomics)
// ---------------------------------------------------------------------------
__global__ __launch_bounds__(256)
void prep_kernel(const float* __restrict__ G,
                 const float* __restrict__ v, const float* __restrict__ w,
                 __hip_bfloat16* __restrict__ Gt,
                 __hip_bfloat16* __restrict__ Pdt,
                 float* __restrict__ S,
                 float* __restrict__ out) {
    const int b = blockIdx.x;
    if (b < 496) {
        __shared__ float tile[64][65];
        const int nTile = b % 62;
        const int mTile = b / 62;          // 0..7
        const int n0 = nTile * 64;
        const int m0 = mTile * 64;
        const int tc = threadIdx.x & 63;
        const int tr = threadIdx.x >> 6;
#pragma unroll
        for (int rr = 0; rr < 64; rr += 4) {
            int n = n0 + tc;
            tile[rr + tr][tc] = (n < LDIM) ? G[(size_t)(m0 + rr + tr) * LDIM + n] : 0.f;
        }
        __syncthreads();
        const int nr = threadIdx.x >> 2;          // n-row within tile
        const int ms = (threadIdx.x & 3) * 16;    // m-segment
        __hip_bfloat16 buf[16];
#pragma unroll
        for (int i = 0; i < 16; ++i)
            buf[i] = __float2bfloat16(tile[ms + i][nr]);
        __hip_bfloat16* dst = Gt + (size_t)(n0 + nr) * MDIM + m0 + ms;
        *reinterpret_cast<uint4*>(dst)     = *reinterpret_cast<uint4*>(&buf[0]);
        *reinterpret_cast<uint4*>(dst + 8) = *reinterpret_cast<uint4*>(&buf[8]);
    } else if (b < 1072) {
        int idx = (b - 496) * 256 + threadIdx.x;   // ko*512 + m, exact range
        int ko = idx >> 9;
        int m  = idx & 511;
        float val = (ko < KO) ? (v[m * KO + ko] - w[m * KO + ko]) : 0.f;
        Pdt[idx] = __float2bfloat16(val);          // coalesced write
    } else if (b < 1552) {
        int idx = (b - 1072) * 256 + threadIdx.x;  // 480*256 = 122880 exact
        S[idx] = 0.f;
    } else {
        int idx = (b - 1552) * 256 + threadIdx.x;  // 20*256 = 5120 exact
        out[idx] = 0.f;
    }
}

// ---------------------------------------------------------------------------
// K1: staged MFMA GEMM (r14-verified) fused with fold:
//   partial T[ko][n] over one K-half -> atomicAdd into S[o, c, pi+i, pj+jk]
//   (scatter map verified rounds 8/9; each (ko,n) hits exactly one S elem).
// Grid 558 = 2 K-halves x (9 kt x 31 nt); 2.2 blocks/CU, 8 waves/CU.
// Bijective XCD swizzle (558 = 6*70 + 2*69); logical order lb = nt*18+kt*2+h
// keeps the 18 blocks sharing a 131KB Gt panel on one XCD (L2-served).
// ---------------------------------------------------------------------------
__global__ __launch_bounds__(256, 2)
void tmfma_kernel(const __hip_bfloat16* __restrict__ Pdt,
                  const __hip_bfloat16* __restrict__ Gt,
                  float* __restrict__ S) {
    const int orig = blockIdx.x;          // 0..557
    const int xcd  = orig & 7;
    const int q8   = orig >> 3;
    const int lb   = (xcd < 6 ? xcd * 70 : 420 + (xcd - 6) * 69) + q8;
    const int half = lb & 1;
    const int kt   = (lb >> 1) % 9;       // ko-tile 0..8
    const int nt   = (lb >> 1) / 9;       // n-tile 0..30
    const int ko0  = kt * 32;
    const int n0   = nt * 128;
    const int mBase = half * 256;         // K-half

    const int tid  = threadIdx.x;
    const int wv   = tid >> 6;
    const int lane = tid & 63;
    const int r16  = lane & 15;
    const int kg   = lane >> 4;            // 0..3

    __shared__ __hip_bfloat16 ldsA[2][32 * LROW];    //  9,216 B
    __shared__ __hip_bfloat16 ldsB[2][128 * LROW];   // 36,864 B

    const int srow  = tid >> 3;            // 0..31
    const int slot  = tid & 7;
    const __hip_bfloat16* pA  = Pdt + (size_t)(ko0 + srow) * MDIM + mBase + slot * 8;
    const __hip_bfloat16* pB0 = Gt + (size_t)(n0 +       srow) * MDIM + mBase + slot * 8;
    const __hip_bfloat16* pB1 = Gt + (size_t)(n0 +  32 + srow) * MDIM + mBase + slot * 8;
    const __hip_bfloat16* pB2 = Gt + (size_t)(n0 +  64 + srow) * MDIM + mBase + slot * 8;
    const __hip_bfloat16* pB3 = Gt + (size_t)(n0 +  96 + srow) * MDIM + mBase + slot * 8;
    const int aoff  = srow * LROW + slot * 8;
    const int boff0 = (      srow) * LROW + slot * 8;
    const int boff1 = ( 32 + srow) * LROW + slot * 8;
    const int boff2 = ( 64 + srow) * LROW + slot * 8;
    const int boff3 = ( 96 + srow) * LROW + slot * 8;

    f32x4 acc00 = {0.f,0.f,0.f,0.f}, acc01 = {0.f,0.f,0.f,0.f};
    f32x4 acc10 = {0.f,0.f,0.f,0.f}, acc11 = {0.f,0.f,0.f,0.f};

    uint4 rA, rB0, rB1, rB2, rB3;

#define LDREGS(t)                                                         \
    do { int k0 = (t) * 64;                                               \
        rA  = *reinterpret_cast<const uint4*>(pA  + k0);                  \
        rB0 = *reinterpret_cast<const uint4*>(pB0 + k0);                  \
        rB1 = *reinterpret_cast<const uint4*>(pB1 + k0);                  \
        rB2 = *reinterpret_cast<const uint4*>(pB2 + k0);                  \
        rB3 = *reinterpret_cast<const uint4*>(pB3 + k0);                  \
    } while (0)

#define WRLDS(bsel)                                                       \
    do {                                                                  \
        *reinterpret_cast<uint4*>(&ldsA[bsel][aoff])  = rA;               \
        *reinterpret_cast<uint4*>(&ldsB[bsel][boff0]) = rB0;              \
        *reinterpret_cast<uint4*>(&ldsB[bsel][boff1]) = rB1;              \
        *reinterpret_cast<uint4*>(&ldsB[bsel][boff2]) = rB2;              \
        *reinterpret_cast<uint4*>(&ldsB[bsel][boff3]) = rB3;              \
    } while (0)

#define COMPUTE(bsel)                                                     \
    do {                                                                  \
        _Pragma("unroll")                                                 \
        for (int ks = 0; ks < 2; ++ks) {                                  \
            int kb = ks * 32 + kg * 8;                                    \
            bfrag a0 = *reinterpret_cast<const bfrag*>(                   \
                &ldsA[bsel][(r16) * LROW + kb]);                          \
            bfrag a1 = *reinterpret_cast<const bfrag*>(                   \
                &ldsA[bsel][(16 + r16) * LROW + kb]);                     \
            bfrag b0 = *reinterpret_cast<const bfrag*>(                   \
                &ldsB[bsel][(wv * 32 + r16) * LROW + kb]);                \
            bfrag b1 = *reinterpret_cast<const bfrag*>(                   \
                &ldsB[bsel][(wv * 32 + 16 + r16) * LROW + kb]);           \
            acc00 = __builtin_amdgcn_mfma_f32_16x16x32_bf16(a0, b0, acc00, 0, 0, 0); \
            acc01 = __builtin_amdgcn_mfma_f32_16x16x32_bf16(a0, b1, acc01, 0, 0, 0); \
            acc10 = __builtin_amdgcn_mfma_f32_16x16x32_bf16(a1, b0, acc10, 0, 0, 0); \
            acc11 = __builtin_amdgcn_mfma_f32_16x16x32_bf16(a1, b1, acc11, 0, 0, 0); \
        }                                                                 \
    } while (0)

    LDREGS(0);
    WRLDS(0);
    __syncthreads();

#pragma unroll
    for (int t = 0; t < 4; ++t) {
        const int cur = t & 1;
        if (t < 3) LDREGS(t + 1);
        COMPUTE(cur);
        if (t < 3) WRLDS(cur ^ 1);
        __syncthreads();
    }
#undef LDREGS
#undef WRLDS
#undef COMPUTE

    // fused fold epilogue: C/D col = lane&15 (n), row = kg*4+reg (ko);
    // scatter S[o*CHW + c*4096 + i*64 + jk + pi*64 + pj], verified r8/r9.
    const f32x4* accs[4] = { &acc00, &acc01, &acc10, &acc11 };
#pragma unroll
    for (int f = 0; f < 2; ++f) {
#pragma unroll
        for (int g = 0; g < 2; ++g) {
            const f32x4 a = *accs[f * 2 + g];
            int col = n0 + wv * 32 + g * 16 + r16;
            if (col < LDIM) {
                int pi  = col / HOg;
                int pj  = col - pi * HOg;
                int off = pi * 64 + pj;
#pragma unroll
                for (int r = 0; r < 4; ++r) {
                    int ro = ko0 + f * 16 + kg * 4 + r;
                    if (ro < KO) {
                        int o   = ro % ODIM;
                        int rem = ro / ODIM;          // 0..26
                        int c   = rem / 9;
                        int ij  = rem - c * 9;
                        int i   = ij / 3;
                        int jk  = ij - i * 3;
                        atomicAdd(&S[o * CHW + c * 4096 + i * 64 + jk + off], a[r]);
                    }
                }
            }
        }
    }
}

// ---------------------------------------------------------------------------
// K2: out[b][o] += sum_{chw in slice} x[b][chw] * S[o][chw]
// Grid 768 = 64 image-octets x 12 chw-slices; S float4 reused for 8 images.
// ---------------------------------------------------------------------------
__global__ __launch_bounds__(256)
void out_gemm_kernel(const float* __restrict__ X,
                     const float* __restrict__ S,
                     float* __restrict__ out) {
    const int bg = blockIdx.x / 12;    // image octet
    const int sl = blockIdx.x % 12;    // chw slice
    const int b0 = bg * 8;
    const int tid = threadIdx.x;
    const int NV = CHW / 4;            // 3072
    const int i  = sl * 256 + tid;     // float4 index

    const float4* X4 = reinterpret_cast<const float4*>(X);
    const float4* S4 = reinterpret_cast<const float4*>(S);

    float acc[8][ODIM];
#pragma unroll
    for (int im = 0; im < 8; ++im)
#pragma unroll
        for (int o = 0; o < ODIM; ++o) acc[im][o] = 0.f;

    float4 xv[8];
#pragma unroll
    for (int im = 0; im < 8; ++im)
        xv[im] = X4[(size_t)(b0 + im) * NV + i];
#pragma unroll
    for (int o = 0; o < ODIM; ++o) {
        float4 sv = S4[(size_t)o * NV + i];
#pragma unroll
        for (int im = 0; im < 8; ++im) {
            acc[im][o] += xv[im].x * sv.x + xv[im].y * sv.y
                        + xv[im].z * sv.z + xv[im].w * sv.w;
        }
    }

#pragma unroll
    for (int im = 0; im < 8; ++im)
#pragma unroll
        for (int o = 0; o < ODIM; ++o) {
            float s = acc[im][o];
            for (int off = 32; off > 0; off >>= 1)
                s += __shfl_down(s, off, 64);
            acc[im][o] = s;
        }

    __shared__ float red[4][80];
    const int wave = tid >> 6;
    const int lane = tid & 63;
    if (lane == 0) {
#pragma unroll
        for (int im = 0; im < 8; ++im)
#pragma unroll
            for (int o = 0; o < ODIM; ++o)
                red[wave][im * ODIM + o] = acc[im][o];
    }
    __syncthreads();
    if (tid < 80) {
        float t = red[0][tid] + red[1][tid] + red[2][tid] + red[3][tid];
        int im = tid / ODIM;
        int o  = tid - im * ODIM;
        atomicAdd(&out[(size_t)(b0 + im) * ODIM + o], t);
    }
}

extern "C" void kernel_launch(void* const* d_in, const int* in_sizes, int n_in,
                              void* d_out, int out_size, void* d_ws, size_t ws_size,
                              hipStream_t stream) {
    const float* x = (const float*)d_in[0];   // (512, 3, 64, 64)
    const float* G = (const float*)d_in[1];   // (512, 3844)
    const float* v = (const float*)d_in[2];   // (512, 27, 10)
    const float* w = (const float*)d_in[3];   // (512, 27, 10)
    float* out = (float*)d_out;               // (512, 10)

    // ws layout (16B-aligned):
    //   S   fp32 [10][12288] =   491,520 B   (atomic-accumulated)
    //   Gt  bf16 [3968][512] = 4,063,232 B
    //   Pdt bf16 [288][512]  =   294,912 B
    char* wsb = (char*)d_ws;
    float*          S   = (float*)wsb;
    __hip_bfloat16* Gt  = (__hip_bfloat16*)(wsb + 491520);
    __hip_bfloat16* Pdt = (__hip_bfloat16*)(wsb + 491520 + 4063232);

    prep_kernel<<<1572, 256, 0, stream>>>(G, v, w, Gt, Pdt, S, out);

    tmfma_kernel<<<558, 256, 0, stream>>>(Pdt, Gt, S);

    out_gemm_kernel<<<768, 256, 0, stream>>>(x, S, out);
}

// Round 16
// 45.354 us; speedup vs baseline: 1.0829x; 1.0829x over previous
//
#include <hip/hip_runtime.h>
#include <hip/hip_bf16.h>

// ConvexReLUCNN: B=512, C=3, H=W=64, KERNEL=3
//   K=27, L=62*62=3844, M=512, O=10
#define ODIM   10
#define HOg    62
#define LDIM   3844
#define CHW    12288
#define BATCH  512
#define KO     270
#define MDIM   512        // reduction dim (neurons)
#define LROW   72         // padded LDS row stride in bf16 (144 B)

typedef __attribute__((ext_vector_type(8))) short bfrag;   // 8 bf16 (4 VGPR)
typedef __attribute__((ext_vector_type(4))) float f32x4;

// ---------------------------------------------------------------------------
// K0 prep, 1092 blocks:
//   [0,496):     Gt[n][m] (bf16) = G[m][n], 64x64 LDS-tiled transpose (n<3968)
//   [496,1072):  Pdt[ko][m] (bf16) = v[m][ko]-w[m][ko]  (ko>=270 -> 0)
//   [1072,1092): out = 0  (out_gemm accumulates with atomics)
// ---------------------------------------------------------------------------
__global__ __launch_bounds__(256)
void prep_kernel(const float* __restrict__ G,
                 const float* __restrict__ v, const float* __restrict__ w,
                 __hip_bfloat16* __restrict__ Gt,
                 __hip_bfloat16* __restrict__ Pdt,
                 float* __restrict__ out) {
    const int b = blockIdx.x;
    if (b < 496) {
        __shared__ float tile[64][65];
        const int nTile = b % 62;
        const int mTile = b / 62;          // 0..7
        const int n0 = nTile * 64;
        const int m0 = mTile * 64;
        const int tc = threadIdx.x & 63;
        const int tr = threadIdx.x >> 6;
#pragma unroll
        for (int rr = 0; rr < 64; rr += 4) {
            int n = n0 + tc;
            tile[rr + tr][tc] = (n < LDIM) ? G[(size_t)(m0 + rr + tr) * LDIM + n] : 0.f;
        }
        __syncthreads();
        const int nr = threadIdx.x >> 2;          // n-row within tile
        const int ms = (threadIdx.x & 3) * 16;    // m-segment
        __hip_bfloat16 buf[16];
#pragma unroll
        for (int i = 0; i < 16; ++i)
            buf[i] = __float2bfloat16(tile[ms + i][nr]);
        __hip_bfloat16* dst = Gt + (size_t)(n0 + nr) * MDIM + m0 + ms;
        *reinterpret_cast<uint4*>(dst)     = *reinterpret_cast<uint4*>(&buf[0]);
        *reinterpret_cast<uint4*>(dst + 8) = *reinterpret_cast<uint4*>(&buf[8]);
    } else if (b < 1072) {
        int idx = (b - 496) * 256 + threadIdx.x;   // ko*512 + m, exact range
        int ko = idx >> 9;
        int m  = idx & 511;
        float val = (ko < KO) ? (v[m * KO + ko] - w[m * KO + ko]) : 0.f;
        Pdt[idx] = __float2bfloat16(val);          // coalesced write
    } else {
        int idx = (b - 1072) * 256 + threadIdx.x;  // 20*256 = 5120 exact
        out[idx] = 0.f;
    }
}

// ---------------------------------------------------------------------------
// K1: T[ko][n] = sum_m Pdt[ko][m]*Gt[n][m]  — m97-style LDS-staged MFMA GEMM.
// Grid 279 = 9 kt x 31 nt (bijective XCD swizzle). Block 256 = 4 waves.
// Tile 32ko x 128n, K-loop 8 x 64, double-buffered padded LDS (144 B rows).
// Best-measured tmfma variant (round 14, total 45.4 us).
// ---------------------------------------------------------------------------
__global__ __launch_bounds__(256, 2)
void tmfma_kernel(const __hip_bfloat16* __restrict__ Pdt,
                  const __hip_bfloat16* __restrict__ Gt,
                  float* __restrict__ T) {
    // bijective XCD swizzle, nwg = 279 = 7*35 + 1*34
    const int orig = blockIdx.x;
    const int xcd  = orig & 7;
    const int q8   = orig >> 3;
    const int lbf  = (xcd < 7 ? xcd * 35 + q8 : 245 + q8);
    const int kt   = lbf % 9;
    const int nt   = lbf / 9;              // 0..30
    const int ko0  = kt * 32;
    const int n0   = nt * 128;

    const int tid  = threadIdx.x;
    const int wv   = tid >> 6;
    const int lane = tid & 63;
    const int r16  = lane & 15;
    const int kg   = lane >> 4;            // 0..3

    __shared__ __hip_bfloat16 ldsA[2][32 * LROW];    //  9,216 B
    __shared__ __hip_bfloat16 ldsB[2][128 * LROW];   // 36,864 B

    const int srow  = tid >> 3;            // 0..31
    const int slot  = tid & 7;
    const __hip_bfloat16* pA  = Pdt + (size_t)(ko0 + srow) * MDIM + slot * 8;
    const __hip_bfloat16* pB0 = Gt + (size_t)(n0 +       srow) * MDIM + slot * 8;
    const __hip_bfloat16* pB1 = Gt + (size_t)(n0 +  32 + srow) * MDIM + slot * 8;
    const __hip_bfloat16* pB2 = Gt + (size_t)(n0 +  64 + srow) * MDIM + slot * 8;
    const __hip_bfloat16* pB3 = Gt + (size_t)(n0 +  96 + srow) * MDIM + slot * 8;
    const int aoff  = srow * LROW + slot * 8;
    const int boff0 = (      srow) * LROW + slot * 8;
    const int boff1 = ( 32 + srow) * LROW + slot * 8;
    const int boff2 = ( 64 + srow) * LROW + slot * 8;
    const int boff3 = ( 96 + srow) * LROW + slot * 8;

    f32x4 acc00 = {0.f,0.f,0.f,0.f}, acc01 = {0.f,0.f,0.f,0.f};
    f32x4 acc10 = {0.f,0.f,0.f,0.f}, acc11 = {0.f,0.f,0.f,0.f};

    uint4 rA, rB0, rB1, rB2, rB3;

#define LDREGS(t)                                                         \
    do { int k0 = (t) * 64;                                               \
        rA  = *reinterpret_cast<const uint4*>(pA  + k0);                  \
        rB0 = *reinterpret_cast<const uint4*>(pB0 + k0);                  \
        rB1 = *reinterpret_cast<const uint4*>(pB1 + k0);                  \
        rB2 = *reinterpret_cast<const uint4*>(pB2 + k0);                  \
        rB3 = *reinterpret_cast<const uint4*>(pB3 + k0);                  \
    } while (0)

#define WRLDS(bsel)                                                       \
    do {                                                                  \
        *reinterpret_cast<uint4*>(&ldsA[bsel][aoff])  = rA;               \
        *reinterpret_cast<uint4*>(&ldsB[bsel][boff0]) = rB0;              \
        *reinterpret_cast<uint4*>(&ldsB[bsel][boff1]) = rB1;              \
        *reinterpret_cast<uint4*>(&ldsB[bsel][boff2]) = rB2;              \
        *reinterpret_cast<uint4*>(&ldsB[bsel][boff3]) = rB3;              \
    } while (0)

#define COMPUTE(bsel)                                                     \
    do {                                                                  \
        _Pragma("unroll")                                                 \
        for (int ks = 0; ks < 2; ++ks) {                                  \
            int kb = ks * 32 + kg * 8;                                    \
            bfrag a0 = *reinterpret_cast<const bfrag*>(                   \
                &ldsA[bsel][(r16) * LROW + kb]);                          \
            bfrag a1 = *reinterpret_cast<const bfrag*>(                   \
                &ldsA[bsel][(16 + r16) * LROW + kb]);                     \
            bfrag b0 = *reinterpret_cast<const bfrag*>(                   \
                &ldsB[bsel][(wv * 32 + r16) * LROW + kb]);                \
            bfrag b1 = *reinterpret_cast<const bfrag*>(                   \
                &ldsB[bsel][(wv * 32 + 16 + r16) * LROW + kb]);           \
            acc00 = __builtin_amdgcn_mfma_f32_16x16x32_bf16(a0, b0, acc00, 0, 0, 0); \
            acc01 = __builtin_amdgcn_mfma_f32_16x16x32_bf16(a0, b1, acc01, 0, 0, 0); \
            acc10 = __builtin_amdgcn_mfma_f32_16x16x32_bf16(a1, b0, acc10, 0, 0, 0); \
            acc11 = __builtin_amdgcn_mfma_f32_16x16x32_bf16(a1, b1, acc11, 0, 0, 0); \
        }                                                                 \
    } while (0)

    LDREGS(0);
    WRLDS(0);
    __syncthreads();

#pragma unroll
    for (int t = 0; t < 8; ++t) {
        const int cur = t & 1;
        if (t < 7) LDREGS(t + 1);
        COMPUTE(cur);
        if (t < 7) WRLDS(cur ^ 1);
        __syncthreads();
    }
#undef LDREGS
#undef WRLDS
#undef COMPUTE

    // epilogue: C/D col = lane&15 (n), row = kg*4+reg (ko)  [verified r8-r14]
    const f32x4* accs[4] = { &acc00, &acc01, &acc10, &acc11 };
#pragma unroll
    for (int f = 0; f < 2; ++f) {
#pragma unroll
        for (int g = 0; g < 2; ++g) {
            const f32x4 a = *accs[f * 2 + g];
            int col = n0 + wv * 32 + g * 16 + r16;
            if (col < LDIM) {
#pragma unroll
                for (int r = 0; r < 4; ++r) {
                    int ro = ko0 + f * 16 + kg * 4 + r;
                    if (ro < KO)
                        T[(size_t)ro * LDIM + col] = a[r];
                }
            }
        }
    }
}

// ---------------------------------------------------------------------------
// K2: fold T (ko, pix) -> S[o][c*4096 + h*64 + w]; each T element read once.
// ---------------------------------------------------------------------------
__global__ __launch_bounds__(256)
void fold_kernel(const float* __restrict__ T, float* __restrict__ S) {
    int idx = blockIdx.x * 256 + threadIdx.x;   // o*CHW + chw
    if (idx >= ODIM * CHW) return;
    int o   = idx / CHW;
    int chw = idx - o * CHW;
    int c = chw >> 12;
    int h = (chw >> 6) & 63;
    int w = chw & 63;

    float s = 0.f;
    for (int i = 0; i < 3; ++i) {
        int pi = h - i;
        if ((unsigned)pi >= HOg) continue;
        for (int j = 0; j < 3; ++j) {
            int pj = w - j;
            if ((unsigned)pj >= HOg) continue;
            int ko = (c * 9 + i * 3 + j) * ODIM + o;
            s += T[(size_t)ko * LDIM + pi * HOg + pj];
        }
    }
    S[idx] = s;
}

// ---------------------------------------------------------------------------
// K3: out[b][o] += sum_{chw in slice} x[b][chw] * S[o][chw]
// Grid 768 = 64 image-octets x 12 chw-slices; S float4 reused for 8 images.
// ---------------------------------------------------------------------------
__global__ __launch_bounds__(256)
void out_gemm_kernel(const float* __restrict__ X,
                     const float* __restrict__ S,
                     float* __restrict__ out) {
    const int bg = blockIdx.x / 12;    // image octet
    const int sl = blockIdx.x % 12;    // chw slice
    const int b0 = bg * 8;
    const int tid = threadIdx.x;
    const int NV = CHW / 4;            // 3072
    const int i  = sl * 256 + tid;     // float4 index

    const float4* X4 = reinterpret_cast<const float4*>(X);
    const float4* S4 = reinterpret_cast<const float4*>(S);

    float acc[8][ODIM];
#pragma unroll
    for (int im = 0; im < 8; ++im)
#pragma unroll
        for (int o = 0; o < ODIM; ++o) acc[im][o] = 0.f;

    float4 xv[8];
#pragma unroll
    for (int im = 0; im < 8; ++im)
        xv[im] = X4[(size_t)(b0 + im) * NV + i];
#pragma unroll
    for (int o = 0; o < ODIM; ++o) {
        float4 sv = S4[(size_t)o * NV + i];
#pragma unroll
        for (int im = 0; im < 8; ++im) {
            acc[im][o] += xv[im].x * sv.x + xv[im].y * sv.y
                        + xv[im].z * sv.z + xv[im].w * sv.w;
        }
    }

#pragma unroll
    for (int im = 0; im < 8; ++im)
#pragma unroll
        for (int o = 0; o < ODIM; ++o) {
            float s = acc[im][o];
            for (int off = 32; off > 0; off >>= 1)
                s += __shfl_down(s, off, 64);
            acc[im][o] = s;
        }

    __shared__ float red[4][80];
    const int wave = tid >> 6;
    const int lane = tid & 63;
    if (lane == 0) {
#pragma unroll
        for (int im = 0; im < 8; ++im)
#pragma unroll
            for (int o = 0; o < ODIM; ++o)
                red[wave][im * ODIM + o] = acc[im][o];
    }
    __syncthreads();
    if (tid < 80) {
        float t = red[0][tid] + red[1][tid] + red[2][tid] + red[3][tid];
        int im = tid / ODIM;
        int o  = tid - im * ODIM;
        atomicAdd(&out[(size_t)(b0 + im) * ODIM + o], t);
    }
}

extern "C" void kernel_launch(void* const* d_in, const int* in_sizes, int n_in,
                              void* d_out, int out_size, void* d_ws, size_t ws_size,
                              hipStream_t stream) {
    const float* x = (const float*)d_in[0];   // (512, 3, 64, 64)
    const float* G = (const float*)d_in[1];   // (512, 3844)
    const float* v = (const float*)d_in[2];   // (512, 27, 10)
    const float* w = (const float*)d_in[3];   // (512, 27, 10)
    float* out = (float*)d_out;               // (512, 10)

    // ws layout (16B-aligned):
    //   T   fp32 [270][3844] = 4,151,520 B
    //   Gt  bf16 [3968][512] = 4,063,232 B
    //   Pdt bf16 [288][512]  =   294,912 B
    //   S   fp32 [10][12288] =   491,520 B
    char* wsb = (char*)d_ws;
    float*          T   = (float*)wsb;
    __hip_bfloat16* Gt  = (__hip_bfloat16*)(wsb + 4151520);
    __hip_bfloat16* Pdt = (__hip_bfloat16*)(wsb + 4151520 + 4063232);
    float*          S   = (float*)(wsb + 4151520 + 4063232 + 294912);

    prep_kernel<<<1092, 256, 0, stream>>>(G, v, w, Gt, Pdt, out);

    tmfma_kernel<<<279, 256, 0, stream>>>(Pdt, Gt, T);

    fold_kernel<<<(ODIM * CHW + 255) / 256, 256, 0, stream>>>(T, S);

    out_gemm_kernel<<<768, 256, 0, stream>>>(x, S, out);
}